// Round 3
// baseline (180.146 us; speedup 1.0000x reference)
//
#include <hip/hip_runtime.h>
#include <hip/hip_bf16.h>

// MaskedContrastiveLoss: loss = 0.5*[mean_i(rowLSE_i - pos_i) + mean_j(colLSE_j - pos_j)]
// logits = (A @ B^T) * (1/0.07), A,B: [256, 65536] fp32, L2-normalized rows.
//
// Structure (2 dispatches total):
//   1) split-K bf16 MFMA GEMM (verified, char-identical since 172µs baseline)
//   2) finalize: block b reduces partials row b (float4-coalesced, wave-split
//      over chunks) -> logits row + rowout[b]; then device-scope fence +
//      atomic counter; the single "last" block computes all column LSEs from
//      logits and writes the scalar output. The mod-256 counter trick makes
//      this graph-replay-safe with NO memset dispatch.

#define D_DIM 65536
#define B_DIM 256
#define LDK 72  // padded LDS row stride (elements) to break bank conflicts

constexpr float TEMP = 1.0f / 0.07f;

typedef short short8 __attribute__((ext_vector_type(8)));
typedef float floatx4 __attribute__((ext_vector_type(4)));

__device__ inline unsigned short f2bf(float f) {
  unsigned u = __builtin_bit_cast(unsigned, f);
  unsigned rounding = 0x7fffu + ((u >> 16) & 1u);  // RNE (inputs are finite/normal)
  return (unsigned short)((u + rounding) >> 16);
}

__device__ inline void st_bf16x4(unsigned short* dst, float4 v) {
  uint2 u;
  u.x = (unsigned)f2bf(v.x) | ((unsigned)f2bf(v.y) << 16);
  u.y = (unsigned)f2bf(v.z) | ((unsigned)f2bf(v.w) << 16);
  *(uint2*)dst = u;
}

// grid = 4*C blocks; block = 256 threads (4 waves).
// blockIdx.x -> (mt in {0,128}, nt in {0,128}, K-chunk)
__global__ __launch_bounds__(256, 2) void gemm_splitk(
    const float* __restrict__ A, const float* __restrict__ Bm,
    float* __restrict__ partials, int Kc) {
  const int bid = blockIdx.x;
  const int mt = (bid & 1) * 128;
  const int nt = ((bid >> 1) & 1) * 128;
  const int chunk = bid >> 2;
  const size_t k0 = (size_t)chunk * (size_t)Kc;

  __shared__ unsigned short As[128][LDK];
  __shared__ unsigned short Bs[128][LDK];

  const int t = threadIdx.x;
  const int lane = t & 63;
  const int w = t >> 6;          // wave 0..3
  const int wm = (w & 1) * 64;   // wave sub-tile origin
  const int wn = (w >> 1) * 64;

  // global staging indexing: 16 threads cover one row's 64 floats (16 x float4)
  const int lr = t >> 4;          // base row 0..15 (+p*16)
  const int lc = (t & 15) * 4;    // col within BK=64

  const float* Abase = A + (size_t)(mt + lr) * D_DIM + k0 + lc;
  const float* Bbase = Bm + (size_t)(nt + lr) * D_DIM + k0 + lc;

  floatx4 acc[4][4];
#pragma unroll
  for (int mb = 0; mb < 4; ++mb)
#pragma unroll
    for (int nb = 0; nb < 4; ++nb) acc[mb][nb] = (floatx4)0.f;

  float4 ra[8], rb[8];
  const int nst = Kc >> 6;  // stages of BK=64

  // prefetch stage 0
#pragma unroll
  for (int p = 0; p < 8; ++p) {
    ra[p] = *(const float4*)(Abase + (size_t)p * 16 * D_DIM);
    rb[p] = *(const float4*)(Bbase + (size_t)p * 16 * D_DIM);
  }

  for (int s = 0; s < nst; ++s) {
    // convert + stage into LDS
#pragma unroll
    for (int p = 0; p < 8; ++p) {
      st_bf16x4(&As[lr + p * 16][lc], ra[p]);
      st_bf16x4(&Bs[lr + p * 16][lc], rb[p]);
    }
    __syncthreads();

    // issue next stage's global loads (overlap with MFMA below)
    if (s + 1 < nst) {
      const float* Ap = Abase + (size_t)(s + 1) * 64;
      const float* Bp = Bbase + (size_t)(s + 1) * 64;
#pragma unroll
      for (int p = 0; p < 8; ++p) {
        ra[p] = *(const float4*)(Ap + (size_t)p * 16 * D_DIM);
        rb[p] = *(const float4*)(Bp + (size_t)p * 16 * D_DIM);
      }
    }

    // MFMA over BK=64 (two K-steps of 32)
#pragma unroll
    for (int ks = 0; ks < 64; ks += 32) {
      short8 af[4], bf[4];
      const int ko = ks + (lane >> 4) * 8;
#pragma unroll
      for (int mb = 0; mb < 4; ++mb)
        af[mb] = *(const short8*)&As[wm + mb * 16 + (lane & 15)][ko];
#pragma unroll
      for (int nb = 0; nb < 4; ++nb)
        bf[nb] = *(const short8*)&Bs[wn + nb * 16 + (lane & 15)][ko];
#pragma unroll
      for (int mb = 0; mb < 4; ++mb)
#pragma unroll
        for (int nb = 0; nb < 4; ++nb)
          acc[mb][nb] = __builtin_amdgcn_mfma_f32_16x16x32_bf16(
              af[mb], bf[nb], acc[mb][nb], 0, 0, 0);
    }
    __syncthreads();
  }

  // epilogue: write partial tile. C/D layout: col=lane&15, row=(lane>>4)*4+reg
  float* outp = partials + (size_t)chunk * (B_DIM * B_DIM);
#pragma unroll
  for (int mb = 0; mb < 4; ++mb) {
#pragma unroll
    for (int nb = 0; nb < 4; ++nb) {
      const int gi0 = mt + wm + mb * 16 + ((lane >> 4) * 4);
      const int gj = nt + wn + nb * 16 + (lane & 15);
#pragma unroll
      for (int r = 0; r < 4; ++r)
        outp[(size_t)(gi0 + r) * B_DIM + gj] = acc[mb][nb][r];
    }
  }
}

// 256 blocks x 256 threads. Block b:
//   - wave q accumulates chunks c = q, q+4, ... of partials row b with
//     float4 loads (lane l covers columns 4l..4l+3) -> LDS combine
//   - logits row b written; rowout[b] = rowLSE_b - 2*pos_b
//   - fence + mod-256 atomic counter; the single last block computes
//     colLSE_j for all j from logits and writes out.
__global__ __launch_bounds__(256) void finalize(
    const float* __restrict__ partials, float* __restrict__ logits,
    float* __restrict__ rowout, unsigned int* __restrict__ counter,
    float* __restrict__ out, int C) {
  const int b = blockIdx.x;
  const int t = threadIdx.x;
  const int q = t >> 6;  // wave
  const int l = t & 63;  // lane

  __shared__ float sums[4][B_DIM];
  __shared__ float wsum[4];
  __shared__ float posv;
  __shared__ int lastflag;

  // wave-split chunk accumulation, float4-coalesced (1KB per wave per chunk)
  float4 s4 = make_float4(0.f, 0.f, 0.f, 0.f);
  const float* pb = partials + (size_t)b * B_DIM + 4 * l;
#pragma unroll 8
  for (int c = q; c < C; c += 4) {
    const float4 v = *(const float4*)(pb + (size_t)c * (B_DIM * B_DIM));
    s4.x += v.x;
    s4.y += v.y;
    s4.z += v.z;
    s4.w += v.w;
  }
  *(float4*)&sums[q][4 * l] = s4;
  __syncthreads();

  const float lg = (sums[0][t] + sums[1][t] + sums[2][t] + sums[3][t]) * TEMP;
  logits[b * B_DIM + t] = lg;
  if (t == b) posv = lg;

  float e = expf(lg);  // |lg| <= 14.3 by Cauchy-Schwarz: no max-shift needed
#pragma unroll
  for (int off = 32; off > 0; off >>= 1) e += __shfl_down(e, off);
  if (l == 0) wsum[q] = e;
  __syncthreads();
  if (t == 0) {
    const float tot = wsum[0] + wsum[1] + wsum[2] + wsum[3];
    rowout[b] = logf(tot) - 2.f * posv;
    // release: make this block's logits row + rowout visible device-wide,
    // then bump the epoch counter. Exactly one block per launch observes
    // (old+1) % 256 == 0 regardless of the counter's initial value, so no
    // memset/zeroing dispatch is needed and graph replay is safe.
    __threadfence();
    const unsigned old = atomicAdd(counter, 1u);
    lastflag = (((old + 1u) & 255u) == 0u);
    __threadfence();  // acquire side for the reads below
  }
  __syncthreads();
  if (!lastflag) return;

  // last block: column LSEs from finalized logits (reads are lane-coalesced:
  // for fixed i, lanes t..t+63 read consecutive floats), then final scalar.
  float csum = 0.f;
#pragma unroll 8
  for (int i = 0; i < B_DIM; ++i) csum += expf(logits[i * B_DIM + t]);
  float v = rowout[t] + logf(csum);
#pragma unroll
  for (int off = 32; off > 0; off >>= 1) v += __shfl_down(v, off);
  if (l == 0) wsum[q] = v;
  __syncthreads();
  if (t == 0)
    out[0] = (wsum[0] + wsum[1] + wsum[2] + wsum[3]) * (0.5f / 256.f);
}

extern "C" void kernel_launch(void* const* d_in, const int* in_sizes, int n_in,
                              void* d_out, int out_size, void* d_ws, size_t ws_size,
                              hipStream_t stream) {
  (void)in_sizes; (void)n_in; (void)out_size;
  const float* A = (const float*)d_in[0];
  const float* Bm = (const float*)d_in[1];
  float* out = (float*)d_out;

  // ws layout: [logits 256*256 f32][partials C*256*256 f32][rowout 256][counter]
  const size_t per = (size_t)B_DIM * B_DIM * sizeof(float);  // 256 KB
  int C = 128;
  while (C > 1 &&
         (size_t)(C + 1) * per + (B_DIM + 16) * sizeof(float) > ws_size)
    C >>= 1;
  const int Kc = D_DIM / C;

  float* logits = (float*)d_ws;
  float* partials = (float*)d_ws + (size_t)B_DIM * B_DIM;
  float* rowout = partials + (size_t)C * B_DIM * B_DIM;
  unsigned int* counter = (unsigned int*)(rowout + B_DIM);

  gemm_splitk<<<4 * C, 256, 0, stream>>>(A, Bm, partials, Kc);
  finalize<<<B_DIM, B_DIM, 0, stream>>>(partials, logits, rowout, counter, out,
                                        C);
}